// Round 2
// baseline (272.462 us; speedup 1.0000x reference)
//
#include <hip/hip_runtime.h>
#include <math.h>

// ---- geometry constants (match reference) ----
constexpr int   VIEWS = 128;
constexpr int   NDET  = 512;
constexpr int   IMG   = 256;
constexpr int   BATCH = 2;
constexpr float SID_F = 750.0f;
constexpr float SDD_F = 1250.0f;
constexpr float DET_ELT = 1.2f;
constexpr float DET_OFF = 0.0f;
constexpr float STEP  = 1.0f;
// R = 256 * sqrt(2)/2 = 181.01933598375618 (double), NS = ceil(2R)+1 = 364
constexpr int   NS = 364;
// t0 = SID - R, rounded through double like the reference
constexpr float T0 = (float)(750.0 - 181.01933598375618);

__global__ __launch_bounds__(256) void fanbeam_fpj(const float* __restrict__ img,
                                                   float* __restrict__ out) {
    const int idx = blockIdx.x * 256 + threadIdx.x;   // [0, B*V*N)
    const int n = idx & (NDET - 1);
    const int v = (idx >> 9) & (VIEWS - 1);
    const int b = idx >> 16;

    // beta = deg2rad(360*v/128): v * pi/64, computed via double constant
    const float beta = (float)((double)v * 0.049087385212340517);
    const float cb = cosf(beta);
    const float sb = sinf(beta);

    const float sx = SID_F * cb;
    const float sy = SID_F * sb;
    const float u  = ((float)n - (float)(NDET - 1) * 0.5f) * DET_ELT + DET_OFF;
    // d = det - src = -SDD*(cb,sb) + u*(-sb,cb), then normalize (f32, like ref)
    float dx = fmaf(-u, sb, -SDD_F * cb);
    float dy = fmaf( u, cb, -SDD_F * sb);
    const float inv = rsqrtf(fmaf(dx, dx, dy * dy));
    dx *= inv;
    dy *= inv;

    const float* __restrict__ xb = img + b * IMG * IMG;
    float acc = 0.0f;

#pragma unroll 4
    for (int s = 0; s < NS; ++s) {
        const float t  = T0 + (float)s;               // STEP = 1
        const float px = fmaf(t, dx, sx);
        const float py = fmaf(t, dy, sy);
        const float jx = px + 127.5f;                 // /PIX + (IMG-1)/2
        const float iy = 127.5f - py;
        const float j0f = floorf(jx);
        const float i0f = floorf(iy);
        const float fj = jx - j0f;
        const float fi = iy - i0f;
        const int j0 = (int)j0f;
        const int i0 = (int)i0f;
        const int j1 = j0 + 1;
        const int i1 = i0 + 1;

        const bool vj0 = ((unsigned)j0 < (unsigned)IMG);
        const bool vj1 = ((unsigned)j1 < (unsigned)IMG);
        const bool vi0 = ((unsigned)i0 < (unsigned)IMG);
        const bool vi1 = ((unsigned)i1 < (unsigned)IMG);

        const int jc0 = min(max(j0, 0), IMG - 1);
        const int jc1 = min(max(j1, 0), IMG - 1);
        const int ic0 = min(max(i0, 0), IMG - 1);
        const int ic1 = min(max(i1, 0), IMG - 1);

        const float m00 = (vi0 && vj0) ? 1.0f : 0.0f;
        const float m01 = (vi0 && vj1) ? 1.0f : 0.0f;
        const float m10 = (vi1 && vj0) ? 1.0f : 0.0f;
        const float m11 = (vi1 && vj1) ? 1.0f : 0.0f;

        const float v00 = xb[ic0 * IMG + jc0] * m00;
        const float v01 = xb[ic0 * IMG + jc1] * m01;
        const float v10 = xb[ic1 * IMG + jc0] * m10;
        const float v11 = xb[ic1 * IMG + jc1] * m11;

        const float top = fmaf(fj, v01 - v00, v00);   // lerp in j
        const float bot = fmaf(fj, v11 - v10, v10);
        acc = fmaf(fi, bot - top, acc + top);         // lerp in i, accumulate
    }

    out[idx] = acc * STEP;
}

extern "C" void kernel_launch(void* const* d_in, const int* in_sizes, int n_in,
                              void* d_out, int out_size, void* d_ws, size_t ws_size,
                              hipStream_t stream) {
    const float* x = (const float*)d_in[0];
    float* out = (float*)d_out;
    const int total = BATCH * VIEWS * NDET;           // 131072
    fanbeam_fpj<<<total / 256, 256, 0, stream>>>(x, out);
}

// Round 3
// 113.890 us; speedup vs baseline: 2.3923x; 2.3923x over previous
//
#include <hip/hip_runtime.h>
#include <math.h>

// ---- geometry constants (match reference) ----
constexpr int   VIEWS = 128;
constexpr int   NDET  = 512;
constexpr int   IMG   = 256;
constexpr int   BATCH = 2;
constexpr float SID_F = 750.0f;
constexpr float SDD_F = 1250.0f;
constexpr float DET_ELT = 1.2f;
constexpr float DET_OFF = 0.0f;
constexpr float STEP  = 1.0f;
constexpr int   NS = 364;                       // ceil(2R)+1, R = 128*sqrt(2)*PIX
constexpr float T0 = (float)(750.0 - 181.01933598375618);  // SID - R

// ---- padded image layout in d_ws ----
constexpr int PAD     = 2;
constexpr int PROWS   = IMG + 2 * PAD;          // 260
constexpr int PSTRIDE = 264;                    // row stride (floats), 258 cols used
constexpr int PSZ     = PROWS * PSTRIDE;        // 68640 floats per batch
constexpr int CHUNKS  = 4;
constexpr int SPC     = NS / CHUNKS;            // 91 samples per chunk

// Build zero-bordered padded copy: rows/cols 2..257 hold the image, rest 0.
__global__ __launch_bounds__(256) void pad_img(const float* __restrict__ src,
                                               float* __restrict__ dst) {
    const int p = blockIdx.x * 256 + threadIdx.x;
    if (p >= BATCH * PSZ) return;
    const int b   = p / PSZ;
    const int rem = p - b * PSZ;
    const int i   = rem / PSTRIDE;
    const int j   = rem - i * PSTRIDE;
    const int si = i - PAD, sj = j - PAD;
    float v = 0.0f;
    if ((unsigned)si < (unsigned)IMG && (unsigned)sj < (unsigned)IMG)
        v = src[(b * IMG + si) * IMG + sj];
    dst[p] = v;
}

// Block = 64 rays x 4 t-chunks. Clamped padded indices reproduce the
// reference's validity-mask semantics exactly (border reads return 0).
__global__ __launch_bounds__(256) void fanbeam_fpj_p(const float* __restrict__ pimg,
                                                     float* __restrict__ out) {
    __shared__ float red[256];
    const int tid   = threadIdx.x;
    const int ray   = blockIdx.x * 64 + (tid & 63);   // [0, B*V*N)
    const int chunk = tid >> 6;
    const int n = ray & (NDET - 1);
    const int v = (ray >> 9) & (VIEWS - 1);
    const int b = ray >> 16;

    const float beta = (float)((double)v * 0.049087385212340517);  // v * pi/64
    const float cb = cosf(beta);
    const float sb = sinf(beta);
    const float u  = ((float)n - 255.5f) * DET_ELT + DET_OFF;
    float dx = fmaf(-u, sb, -SDD_F * cb);
    float dy = fmaf( u, cb, -SDD_F * sb);
    const float inv = rsqrtf(fmaf(dx, dx, dy * dy));
    dx *= inv;
    dy *= inv;
    const float cx = fmaf(SID_F, cb, 127.5f);         // jx = t*dx + cx
    const float cy = 127.5f - SID_F * sb;             // iy = t*(-dy) + cy

    const float* __restrict__ pb = pimg + b * PSZ;
    float acc = 0.0f;
    const int s0 = chunk * SPC;

#pragma unroll 4
    for (int s = 0; s < SPC; ++s) {
        const float t  = T0 + (float)(s0 + s);
        const float jx = fmaf(t, dx, cx);
        const float iy = fmaf(t, -dy, cy);
        const float j0f = floorf(jx);
        const float i0f = floorf(iy);
        const float fj = jx - j0f;
        const float fi = iy - i0f;
        int jp = (int)j0f + PAD;
        int ip = (int)i0f + PAD;
        jp = min(max(jp, 0), IMG + PAD);              // 0..258
        ip = min(max(ip, 0), IMG + PAD);
        const float* base = pb + (ip * PSTRIDE + jp);
        const float v00 = base[0];
        const float v01 = base[1];
        const float v10 = base[PSTRIDE];
        const float v11 = base[PSTRIDE + 1];
        const float top = fmaf(fj, v01 - v00, v00);
        const float bot = fmaf(fj, v11 - v10, v10);
        acc = fmaf(fi, bot - top, acc + top);
    }

    red[tid] = acc;
    __syncthreads();
    if (tid < 64) {
        const float r = red[tid] + red[tid + 64] + red[tid + 128] + red[tid + 192];
        out[ray] = r * STEP;
    }
}

// Fallback (round-2 kernel) if ws_size is too small for the padded image.
__global__ __launch_bounds__(256) void fanbeam_fpj(const float* __restrict__ img,
                                                   float* __restrict__ out) {
    const int idx = blockIdx.x * 256 + threadIdx.x;
    const int n = idx & (NDET - 1);
    const int v = (idx >> 9) & (VIEWS - 1);
    const int b = idx >> 16;
    const float beta = (float)((double)v * 0.049087385212340517);
    const float cb = cosf(beta), sb = sinf(beta);
    const float sx = SID_F * cb, sy = SID_F * sb;
    const float u  = ((float)n - 255.5f) * DET_ELT + DET_OFF;
    float dx = fmaf(-u, sb, -SDD_F * cb);
    float dy = fmaf( u, cb, -SDD_F * sb);
    const float inv = rsqrtf(fmaf(dx, dx, dy * dy));
    dx *= inv; dy *= inv;
    const float* __restrict__ xb = img + b * IMG * IMG;
    float acc = 0.0f;
#pragma unroll 4
    for (int s = 0; s < NS; ++s) {
        const float t  = T0 + (float)s;
        const float jx = fmaf(t, dx, sx) + 127.5f;
        const float iy = 127.5f - fmaf(t, dy, sy);
        const float j0f = floorf(jx), i0f = floorf(iy);
        const float fj = jx - j0f, fi = iy - i0f;
        const int j0 = (int)j0f, i0 = (int)i0f;
        const int j1 = j0 + 1, i1 = i0 + 1;
        const bool vj0 = ((unsigned)j0 < (unsigned)IMG);
        const bool vj1 = ((unsigned)j1 < (unsigned)IMG);
        const bool vi0 = ((unsigned)i0 < (unsigned)IMG);
        const bool vi1 = ((unsigned)i1 < (unsigned)IMG);
        const int jc0 = min(max(j0, 0), IMG - 1), jc1 = min(max(j1, 0), IMG - 1);
        const int ic0 = min(max(i0, 0), IMG - 1), ic1 = min(max(i1, 0), IMG - 1);
        const float v00 = xb[ic0 * IMG + jc0] * ((vi0 && vj0) ? 1.0f : 0.0f);
        const float v01 = xb[ic0 * IMG + jc1] * ((vi0 && vj1) ? 1.0f : 0.0f);
        const float v10 = xb[ic1 * IMG + jc0] * ((vi1 && vj0) ? 1.0f : 0.0f);
        const float v11 = xb[ic1 * IMG + jc1] * ((vi1 && vj1) ? 1.0f : 0.0f);
        const float top = fmaf(fj, v01 - v00, v00);
        const float bot = fmaf(fj, v11 - v10, v10);
        acc = fmaf(fi, bot - top, acc + top);
    }
    out[idx] = acc * STEP;
}

extern "C" void kernel_launch(void* const* d_in, const int* in_sizes, int n_in,
                              void* d_out, int out_size, void* d_ws, size_t ws_size,
                              hipStream_t stream) {
    const float* x = (const float*)d_in[0];
    float* out = (float*)d_out;
    const size_t need = (size_t)BATCH * PSZ * sizeof(float);   // 549,120 B
    if (ws_size >= need) {
        float* pimg = (float*)d_ws;
        const int ptotal = BATCH * PSZ;
        pad_img<<<(ptotal + 255) / 256, 256, 0, stream>>>(x, pimg);
        fanbeam_fpj_p<<<(BATCH * VIEWS * NDET) / 64, 256, 0, stream>>>(pimg, out);
    } else {
        fanbeam_fpj<<<(BATCH * VIEWS * NDET) / 256, 256, 0, stream>>>(x, out);
    }
}

// Round 5
// 95.160 us; speedup vs baseline: 2.8632x; 1.1968x over previous
//
#include <hip/hip_runtime.h>
#include <hip/hip_fp16.h>
#include <math.h>

// ---- geometry constants (match reference) ----
constexpr int   VIEWS = 128;
constexpr int   NDET  = 512;
constexpr int   IMG   = 256;
constexpr int   BATCH = 2;
constexpr float SID_F = 750.0f;
constexpr float SDD_F = 1250.0f;
constexpr float DET_ELT = 1.2f;
constexpr float DET_OFF = 0.0f;
constexpr float STEP  = 1.0f;
constexpr int   NS = 364;                       // ceil(2R)+1, R = 128*sqrt(2)
constexpr float T0 = (float)(750.0 - 181.01933598375618);  // SID - R

// ---- LDS fp16 tile: one batch image with 2-px zero border ----
constexpr int PAD    = 2;
constexpr int TROWS  = IMG + 2 * PAD;           // 260
constexpr int TSTR   = 262;                     // halfs per row (word stride 131, odd)
constexpr int TWSTR  = TSTR / 2;                // 131 words per row
constexpr int TWORDS = TROWS * TWSTR;           // 34060 dwords = 136,240 B
constexpr int SPC    = NS / 2;                  // 182 samples per chunk

// Block = one (b, view): 1024 threads = 512 detectors x 2 t-chunks.
// 136 KB static LDS -> 1 block/CU (16 waves). Bilinear sample = 2 ds_read_b32
// pairs + funnel shift (fp16 pixel pairs), zero border replaces masking.
__global__ __launch_bounds__(1024) void fanbeam_lds(const float* __restrict__ img,
                                                    float* __restrict__ out) {
    __shared__ unsigned int tile32[TWORDS];     // fp16 pairs, zero-bordered
    __shared__ float red[1024];
    const int tid = threadIdx.x;
    const int blk = blockIdx.x;                 // = b*VIEWS + v
    const int v = blk & (VIEWS - 1);
    const int b = blk >> 7;

    // ---- stage image into LDS as fp16 (zero border first) ----
    for (int k = tid; k < TWORDS; k += 1024) tile32[k] = 0u;
    __syncthreads();
    const float* __restrict__ src = img + b * IMG * IMG;
    for (int k = tid; k < (IMG * IMG) / 4; k += 1024) {   // 16 iters, float4 coalesced
        const int p = k * 4;
        const int i = p >> 8;
        const int j = p & 255;
        const float4 f = *reinterpret_cast<const float4*>(src + p);
        const unsigned lo = ((unsigned)__half_as_ushort(__float2half(f.y)) << 16)
                          |  (unsigned)__half_as_ushort(__float2half(f.x));
        const unsigned hi = ((unsigned)__half_as_ushort(__float2half(f.w)) << 16)
                          |  (unsigned)__half_as_ushort(__float2half(f.z));
        const int h = (i + PAD) * TSTR + (j + PAD);       // even (j % 4 == 0)
        tile32[h >> 1]       = lo;
        tile32[(h >> 1) + 1] = hi;
    }
    __syncthreads();

    // ---- per-ray geometry (identical arithmetic to the passing round-3 kernel) ----
    const int n     = tid & (NDET - 1);
    const int chunk = tid >> 9;
    const float beta = (float)((double)v * 0.049087385212340517);  // v * pi/64
    const float cb = cosf(beta);
    const float sb = sinf(beta);
    const float u  = ((float)n - 255.5f) * DET_ELT + DET_OFF;
    float dx = fmaf(-u, sb, -SDD_F * cb);
    float dy = fmaf( u, cb, -SDD_F * sb);
    const float inv = rsqrtf(fmaf(dx, dx, dy * dy));
    dx *= inv;
    dy *= inv;
    const float cx = fmaf(SID_F, cb, 127.5f);   // jx = t*dx + cx
    const float cy = 127.5f - SID_F * sb;       // iy = t*(-dy) + cy

    float acc = 0.0f;
    const int s0 = chunk * SPC;

#pragma unroll 4
    for (int s = 0; s < SPC; ++s) {
        const float t  = T0 + (float)(s0 + s);
        const float jx = fmaf(t, dx, cx);
        const float iy = fmaf(t, -dy, cy);
        const float j0f = floorf(jx);
        const float i0f = floorf(iy);
        const float fj = jx - j0f;
        const float fi = iy - i0f;
        int jp = (int)j0f + PAD;
        int ip = (int)i0f + PAD;
        jp = min(max(jp, 0), IMG + PAD);        // 0..258 (border cols are zero)
        ip = min(max(ip, 0), IMG + PAD);
        const int w  = ip * TWSTR + (jp >> 1);  // dword index of pair start
        const unsigned w0 = tile32[w];
        const unsigned w1 = tile32[w + 1];
        const unsigned w2 = tile32[w + TWSTR];
        const unsigned w3 = tile32[w + TWSTR + 1];
        const int sh = (jp & 1) << 4;           // funnel-shift to (jp, jp+1) pair
        const unsigned ptop = (unsigned)((((unsigned long long)w1 << 32) | w0) >> sh);
        const unsigned pbot = (unsigned)((((unsigned long long)w3 << 32) | w2) >> sh);
        const float2 ft = __half22float2(*reinterpret_cast<const __half2*>(&ptop));
        const float2 fb = __half22float2(*reinterpret_cast<const __half2*>(&pbot));
        const float top = fmaf(fj, ft.y - ft.x, ft.x);
        const float bot = fmaf(fj, fb.y - fb.x, fb.x);
        acc = fmaf(fi, bot - top, acc + top);
    }

    red[tid] = acc;
    __syncthreads();
    if (tid < 512) {
        out[blk * 512 + tid] = (red[tid] + red[tid + 512]) * STEP;
    }
}

extern "C" void kernel_launch(void* const* d_in, const int* in_sizes, int n_in,
                              void* d_out, int out_size, void* d_ws, size_t ws_size,
                              hipStream_t stream) {
    const float* x = (const float*)d_in[0];
    float* out = (float*)d_out;
    fanbeam_lds<<<BATCH * VIEWS, 1024, 0, stream>>>(x, out);
}

// Round 6
// 81.468 us; speedup vs baseline: 3.3444x; 1.1681x over previous
//
#include <hip/hip_runtime.h>
#include <hip/hip_fp16.h>
#include <math.h>

// ---- geometry constants (match reference) ----
constexpr int   VIEWS = 128;
constexpr int   NDET  = 512;
constexpr int   IMG   = 256;
constexpr int   BATCH = 2;
constexpr float SID_F = 750.0f;
constexpr float SDD_F = 1250.0f;
constexpr float DET_ELT = 1.2f;
constexpr float DET_OFF = 0.0f;
constexpr float STEP  = 1.0f;
constexpr int   NS = 364;                       // ceil(2R)+1, R = 128*sqrt(2)
constexpr float T0 = (float)(750.0 - 181.01933598375618);  // SID - R

// ---- LDS fp16 tile: one batch image with 2-px zero border ----
constexpr int PAD    = 2;
constexpr int TROWS  = IMG + 2 * PAD;           // 260
constexpr int TSTR   = 262;                     // halfs per row
constexpr int TWSTR  = TSTR / 2;                // 131 words per row (odd: bank spread)
constexpr int TWORDS = TROWS * TWSTR;           // 34060 dwords = 136,240 B

// Block = one (b, view): 1024 threads = 512 detectors x 2 t-chunks.
// Slab test trims each ray to its image-box intersection (~55% of samples);
// skipped samples are exact zeros. Per-sample numerics identical to the
// passing round-5 kernel.
__global__ __launch_bounds__(1024) void fanbeam_lds(const float* __restrict__ img,
                                                    float* __restrict__ out) {
    __shared__ unsigned int tile32[TWORDS];     // fp16 pairs, zero-bordered
    __shared__ float red[1024];
    const int tid = threadIdx.x;
    const int blk = blockIdx.x;                 // = b*VIEWS + v
    const int v = blk & (VIEWS - 1);
    const int b = blk >> 7;

    // ---- border zero-fill (rows 0,1,258,259 fully; cols-words 0,129,130 of rows 2..257)
    for (int k = tid; k < 524 + 768; k += 1024) {
        int w;
        if (k < 524) {                          // 4 border rows x 131 words
            const int r = k / 131, c = k - r * 131;
            const int row = (r < 2) ? r : 256 + r;      // 0,1,258,259
            w = row * TWSTR + c;
        } else {                                // side borders of interior rows
            const int kk = k - 524;             // 0..767
            const int row = 2 + kk / 3;
            const int m = kk % 3;               // 0 -> word 0; 1,2 -> words 129,130
            w = row * TWSTR + ((m == 0) ? 0 : 128 + m);
        }
        tile32[w] = 0u;
    }

    // ---- stage image into LDS as fp16 (interior words 1..128 of rows 2..257)
    const float* __restrict__ src = img + b * IMG * IMG;
    for (int k = tid; k < (IMG * IMG) / 4; k += 1024) {   // 16 iters, float4 coalesced
        const int p = k * 4;
        const int i = p >> 8;
        const int j = p & 255;
        const float4 f = *reinterpret_cast<const float4*>(src + p);
        const unsigned lo = ((unsigned)__half_as_ushort(__float2half(f.y)) << 16)
                          |  (unsigned)__half_as_ushort(__float2half(f.x));
        const unsigned hi = ((unsigned)__half_as_ushort(__float2half(f.w)) << 16)
                          |  (unsigned)__half_as_ushort(__float2half(f.z));
        const int h = (i + PAD) * TSTR + (j + PAD);       // even (j % 4 == 0)
        tile32[h >> 1]       = lo;
        tile32[(h >> 1) + 1] = hi;
    }
    __syncthreads();

    // ---- per-ray geometry (identical arithmetic to round-5 kernel) ----
    const int n     = tid & (NDET - 1);
    const int chunk = tid >> 9;
    const float beta = (float)((double)v * 0.049087385212340517);  // v * pi/64
    const float cb = cosf(beta);
    const float sb = sinf(beta);
    const float u  = ((float)n - 255.5f) * DET_ELT + DET_OFF;
    float dx = fmaf(-u, sb, -SDD_F * cb);
    float dy = fmaf( u, cb, -SDD_F * sb);
    const float inv = rsqrtf(fmaf(dx, dx, dy * dy));
    dx *= inv;
    dy *= inv;
    const float ndy = -dy;
    const float sx = SID_F * cb;
    const float sy = SID_F * sb;
    const float cx = sx + 127.5f;               // jx = t*dx + cx
    const float cy = 127.5f - sy;               // iy = t*ndy + cy

    // ---- slab test: t-range where px,py in [-129.5, 129.5] (conservative) ----
    // Outside that window every bilinear corner is border-zero -> contribution 0.
    const float invx = 1.0f / dx;               // +-inf ok; NaN drops out of min/max
    const float invy = 1.0f / dy;
    const float ta = (-129.5f - sx) * invx, tb = (129.5f - sx) * invx;
    const float tc = (-129.5f - sy) * invy, td = (129.5f - sy) * invy;
    const float txmin = fminf(ta, tb), txmax = fmaxf(ta, tb);
    const float tymin = fminf(tc, td), tymax = fmaxf(tc, td);
    const float tmin = fmaxf(fmaxf(txmin, tymin), T0);
    const float tmax = fminf(fminf(txmax, tymax), T0 + (float)(NS - 1));
    int slo = (int)ceilf(tmin - T0);
    int shi = (int)floorf(tmax - T0);
    slo = max(slo, 0);
    shi = min(shi, NS - 1);

    float acc = 0.0f;
    float sf = (float)(slo + chunk);
#pragma unroll 4
    for (int s = slo + chunk; s <= shi; s += 2) {
        const float t  = T0 + sf;
        sf += 2.0f;                              // exact (integer-valued floats)
        float jx = fmaf(t, dx, cx);
        float iy = fmaf(t, ndy, cy);
        // med3 clamp: safety net; bounds keep all LDS indices in-tile,
        // clamped samples read only zero border.
        jx = fminf(fmaxf(jx, -1.75f), 257.5f);
        iy = fminf(fmaxf(iy, -1.75f), 256.5f);
        const float j0f = floorf(jx);
        const float i0f = floorf(iy);
        const float fj = jx - j0f;
        const float fi = iy - i0f;
        const int jp = (int)j0f + PAD;           // 0..259
        const int ip = (int)i0f + PAD;           // 0..258
        const int w  = ip * TWSTR + (jp >> 1);
        const unsigned w0 = tile32[w];
        const unsigned w1 = tile32[w + 1];
        const unsigned w2 = tile32[w + TWSTR];
        const unsigned w3 = tile32[w + TWSTR + 1];
        const unsigned sh = (unsigned)(jp & 1) << 4;
        const unsigned ptop = __builtin_amdgcn_alignbit(w1, w0, sh);
        const unsigned pbot = __builtin_amdgcn_alignbit(w3, w2, sh);
        const __half2 ht = *reinterpret_cast<const __half2*>(&ptop);
        const __half2 hb = *reinterpret_cast<const __half2*>(&pbot);
        const float t0v = __low2float(ht), t1v = __high2float(ht);
        const float b0v = __low2float(hb), b1v = __high2float(hb);
        const float top = fmaf(fj, t1v - t0v, t0v);
        const float bot = fmaf(fj, b1v - b0v, b0v);
        acc = fmaf(fi, bot - top, acc + top);
    }

    red[tid] = acc;
    __syncthreads();
    if (tid < 512) {
        out[blk * 512 + tid] = (red[tid] + red[tid + 512]) * STEP;
    }
}

extern "C" void kernel_launch(void* const* d_in, const int* in_sizes, int n_in,
                              void* d_out, int out_size, void* d_ws, size_t ws_size,
                              hipStream_t stream) {
    const float* x = (const float*)d_in[0];
    float* out = (float*)d_out;
    fanbeam_lds<<<BATCH * VIEWS, 1024, 0, stream>>>(x, out);
}

// Round 9
// 76.945 us; speedup vs baseline: 3.5410x; 1.0588x over previous
//
#include <hip/hip_runtime.h>
#include <hip/hip_fp16.h>
#include <math.h>
#include <string.h>

// ---- geometry constants (match reference) ----
constexpr int   VIEWS = 128;
constexpr int   NDET  = 512;
constexpr int   IMG   = 256;
constexpr int   BATCH = 2;
constexpr float SID_F = 750.0f;
constexpr float SDD_F = 1250.0f;
constexpr float DET_ELT = 1.2f;
constexpr float DET_OFF = 0.0f;
constexpr float STEP  = 1.0f;
constexpr int   NS = 364;                       // ceil(2R)+1, R = 128*sqrt(2)
constexpr float T0 = (float)(750.0 - 181.01933598375618);  // SID - R

// ---- LDS fp16 tile: one batch image with 2-px zero border ----
constexpr int PAD    = 2;
constexpr int TROWS  = IMG + 2 * PAD;           // 260
constexpr int TSTR   = 262;                     // halfs per row
constexpr int TWSTR  = TSTR / 2;                // 131 words per row (odd: bank spread)
constexpr int TWORDS = TROWS * TWSTR;           // 34060 dwords = 136,240 B

typedef _Float16 h2 __attribute__((ext_vector_type(2)));   // native packed arithmetic
using v2h = decltype(__builtin_amdgcn_cvt_pkrtz(0.0f, 0.0f));  // builtin's __fp16 vec

// Block = one (b, view): 1024 threads = 512 detectors x 2 t-chunks.
// Slab test (+-128.75) trims rays to their image-box span; skipped samples are
// provably zero in the reference (all bilinear corners invalid), and the
// tightened bound keeps every LDS access in-tile WITHOUT per-sample clamps.
// Bilinear = 2x ds_read2_b32 + alignbit/perm repack + packed-fp16 lerp.
__global__ __launch_bounds__(1024) void fanbeam_lds(const float* __restrict__ img,
                                                    float* __restrict__ out) {
    __shared__ unsigned int tile32[TWORDS];     // fp16 pairs, zero-bordered
    __shared__ float red[1024];
    const int tid = threadIdx.x;
    const int blk = blockIdx.x;                 // = b*VIEWS + v
    const int v = blk & (VIEWS - 1);
    const int b = blk >> 7;

    // ---- border zero-fill (rows 0,1,258,259 fully; words 0,129,130 of rows 2..257)
    for (int k = tid; k < 524 + 768; k += 1024) {
        int w;
        if (k < 524) {
            const int r = k / 131, c = k - r * 131;
            const int row = (r < 2) ? r : 256 + r;      // 0,1,258,259
            w = row * TWSTR + c;
        } else {
            const int kk = k - 524;
            const int row = 2 + kk / 3;
            const int m = kk % 3;
            w = row * TWSTR + ((m == 0) ? 0 : 128 + m);
        }
        tile32[w] = 0u;
    }

    // ---- stage image into LDS as fp16 (interior words 1..128 of rows 2..257)
    const float* __restrict__ src = img + b * IMG * IMG;
    for (int k = tid; k < (IMG * IMG) / 4; k += 1024) {   // 16 iters, float4 coalesced
        const int p = k * 4;
        const int i = p >> 8;
        const int j = p & 255;
        const float4 f = *reinterpret_cast<const float4*>(src + p);
        const unsigned lo = ((unsigned)__half_as_ushort(__float2half(f.y)) << 16)
                          |  (unsigned)__half_as_ushort(__float2half(f.x));
        const unsigned hi = ((unsigned)__half_as_ushort(__float2half(f.w)) << 16)
                          |  (unsigned)__half_as_ushort(__float2half(f.z));
        const int h = (i + PAD) * TSTR + (j + PAD);       // even
        tile32[h >> 1]       = lo;
        tile32[(h >> 1) + 1] = hi;
    }
    __syncthreads();

    // ---- per-ray geometry ----
    const int n     = tid & (NDET - 1);
    const int chunk = tid >> 9;
    const float beta = (float)((double)v * 0.049087385212340517);  // v * pi/64
    const float cb = cosf(beta);
    const float sb = sinf(beta);
    const float u  = ((float)n - 255.5f) * DET_ELT + DET_OFF;
    float dx = fmaf(-u, sb, -SDD_F * cb);
    float dy = fmaf( u, cb, -SDD_F * sb);
    const float inv = rsqrtf(fmaf(dx, dx, dy * dy));
    dx *= inv;
    dy *= inv;
    const float ndy = -dy;
    const float sx = SID_F * cb;
    const float sy = SID_F * sb;
    // biased tile coords: jx2 = t*dx + (sx+127.5+PAD); fold t = T0 + sf:
    const float cx3 = fmaf(T0, dx,  sx + 127.5f + (float)PAD);   // jx2 = sf*dx + cx3
    const float cy3 = fmaf(T0, ndy, 127.5f - sy + (float)PAD);   // iy2 = sf*ndy + cy3

    // ---- slab: t-range where |px|,|py| <= 128.75 ----
    // Outside: all 4 bilinear corners invalid in the reference -> exact 0.
    // Inside: jp,ip in [0,258] -> all LDS reads in-tile, no clamps needed.
    const float invx = 1.0f / dx;
    const float invy = 1.0f / dy;
    const float ta = (-128.75f - sx) * invx, tb = (128.75f - sx) * invx;
    const float tc = (-128.75f - sy) * invy, td = (128.75f - sy) * invy;
    const float txmin = fminf(ta, tb), txmax = fmaxf(ta, tb);
    const float tymin = fminf(tc, td), tymax = fmaxf(tc, td);
    const float tmin = fmaxf(fmaxf(txmin, tymin), T0);
    const float tmax = fminf(fminf(txmax, tymax), T0 + (float)(NS - 1));
    int slo = (int)ceilf(tmin - T0);
    int shi = (int)floorf(tmax - T0);
    slo = max(slo, 0);
    shi = min(shi, NS - 1);

    float acc = 0.0f;
    const int start = slo + chunk;
    // ROUND-8 BUG FIX: (shi-start)/2 + 1 gave iters=1 for shi-start==-1
    // (truncating div), executing one OUT-OF-SLAB sample -> OOB LDS read ->
    // stale-LDS divergence on graph replay. (d+2)/2 with max(0,..) is exact:
    // d>=0 -> d/2+1; all d<0 -> 0.
    const int iters = max(0, (shi - start + 2) / 2);
    float sfv = (float)start;

#pragma unroll 4
    for (int k = 0; k < iters; ++k) {
        const float jx2 = fmaf(sfv, dx, cx3);   // in [0.75, 258.25]
        const float iy2 = fmaf(sfv, ndy, cy3);
        sfv += 2.0f;                            // exact
        const int jp = (int)jx2;                // trunc == floor (positive)
        const int ip = (int)iy2;
        const float fj = jx2 - (float)jp;
        const float fi = iy2 - (float)ip;
        const int w = ip * TWSTR + (jp >> 1);
        const unsigned w0 = tile32[w];
        const unsigned w1 = tile32[w + 1];
        const unsigned w2 = tile32[w + TWSTR];
        const unsigned w3 = tile32[w + TWSTR + 1];
        const unsigned sh = (unsigned)jp << 4;  // alignbit uses shift[4:0]
        const unsigned ptop = __builtin_amdgcn_alignbit(w1, w0, sh);  // (t0,t1)
        const unsigned pbot = __builtin_amdgcn_alignbit(w3, w2, sh);  // (b0,b1)
        // repack: L=(t0,b0), H=(t1,b1)
        const unsigned Lu = __builtin_amdgcn_perm(pbot, ptop, 0x05040100u);
        const unsigned Hu = __builtin_amdgcn_perm(pbot, ptop, 0x07060302u);
        const h2 L = __builtin_bit_cast(h2, Lu);
        const h2 H = __builtin_bit_cast(h2, Hu);
        const h2 fj2 = __builtin_bit_cast(h2, __builtin_amdgcn_cvt_pkrtz(fj, fj));
        const h2 r = fj2 * (H - L) + L;         // v_pk_fma: (top, bot)
#if __has_builtin(__builtin_amdgcn_fdot2)
        const h2 wv = __builtin_bit_cast(h2, __builtin_amdgcn_cvt_pkrtz(1.0f - fi, fi));
        acc = __builtin_amdgcn_fdot2(__builtin_bit_cast(v2h, r),
                                     __builtin_bit_cast(v2h, wv), acc, false);
#else
        const float top = (float)r.x;
        const float bot = (float)r.y;
        acc = fmaf(fi, bot - top, acc + top);
#endif
    }

    red[tid] = acc;
    __syncthreads();
    if (tid < 512) {
        out[blk * 512 + tid] = (red[tid] + red[tid + 512]) * STEP;
    }
}

extern "C" void kernel_launch(void* const* d_in, const int* in_sizes, int n_in,
                              void* d_out, int out_size, void* d_ws, size_t ws_size,
                              hipStream_t stream) {
    const float* x = (const float*)d_in[0];
    float* out = (float*)d_out;
    fanbeam_lds<<<BATCH * VIEWS, 1024, 0, stream>>>(x, out);
}